// Round 11
// baseline (554.855 us; speedup 1.0000x reference)
//
#include <hip/hip_runtime.h>

typedef __attribute__((ext_vector_type(8))) short bf16x8;
typedef __attribute__((ext_vector_type(8))) unsigned short u16x8;
typedef __attribute__((ext_vector_type(4))) float f32x4;
typedef __attribute__((ext_vector_type(2))) unsigned uint2v;
typedef __attribute__((ext_vector_type(4))) unsigned uint4v;

#define DEVINL __device__ __forceinline__

constexpr int TB = 2;        // batch
constexpr int TT = 4096;     // seq len
constexpr int TD = 512;      // model dim
constexpr int TH = 8;        // heads
constexpr int THD = 64;      // head dim
constexpr int TM = TB * TT;  // 8192 flattened rows

// fp32 -> bf16 round-to-nearest-even
DEVINL unsigned short f2b(float f) {
  unsigned u = __builtin_bit_cast(unsigned, f);
  u += 0x7FFFu + ((u >> 16) & 1u);
  return (unsigned short)(u >> 16);
}

// pack 2 f32 -> 2 bf16 in one dword (lo -> low16, hi -> high16), RNE
DEVINL unsigned cvtpk(float lo, float hi) {
  unsigned r;
  asm("v_cvt_pk_bf16_f32 %0, %1, %2" : "=v"(r) : "v"(lo), "v"(hi));
  return r;
}

// barrier that only waits LDS ops (global stores may stay in flight)
DEVINL void lgkm_barrier() {
  asm volatile("s_waitcnt lgkmcnt(0)" ::: "memory");
  __builtin_amdgcn_s_barrier();
  __builtin_amdgcn_sched_barrier(0);
}

// ---------------------------------------------------------------------------
// Fused Q/K/V projection (unchanged from r10).
// ---------------------------------------------------------------------------
__global__ __launch_bounds__(256, 2)
void proj_qkv(const float* __restrict__ Xq, const float* __restrict__ Xk,
              const float* __restrict__ Xv, const float* __restrict__ Wq,
              const float* __restrict__ Wk, const float* __restrict__ Wv,
              unsigned short* __restrict__ qb, unsigned short* __restrict__ kb,
              unsigned short* __restrict__ vt)
{
  constexpr int K = TD, N = TD;
  __shared__ unsigned short As[128][72];
  __shared__ unsigned short Bs[128][72];

  const int z = blockIdx.z;
  const float* X = (z == 0) ? Xq : (z == 1) ? Xk : Xv;
  const float* W = (z == 0) ? Wq : (z == 1) ? Wk : Wv;
  unsigned short* Yb = (z == 0) ? qb : (z == 1) ? kb : vt;
  const bool TR = (z == 2);

  const int t    = threadIdx.x;
  const int lane = t & 63, w = t >> 6;
  const int fr = lane & 15, fq = lane >> 4;
  const int wr = (w >> 1) * 64, wc = (w & 1) * 64;
  const int bm = blockIdx.x * 128, bn = blockIdx.y * 128;
  const int srow = t >> 1;
  const int skh  = (t & 1) * 32;

  f32x4 acc[4][4];
  #pragma unroll
  for (int i = 0; i < 4; ++i)
    #pragma unroll
    for (int j = 0; j < 4; ++j)
      acc[i][j] = f32x4{0.f, 0.f, 0.f, 0.f};

  for (int k0 = 0; k0 < K; k0 += 64) {
    const float* srcA = X + (size_t)(bm + srow) * K + k0 + skh;
    const float* srcB = W + (size_t)(bn + srow) * K + k0 + skh;
    #pragma unroll
    for (int i = 0; i < 4; ++i) {
      float4 a0 = ((const float4*)srcA)[2 * i];
      float4 a1 = ((const float4*)srcA)[2 * i + 1];
      u16x8 oa = {f2b(a0.x), f2b(a0.y), f2b(a0.z), f2b(a0.w),
                  f2b(a1.x), f2b(a1.y), f2b(a1.z), f2b(a1.w)};
      *(u16x8*)&As[srow][skh + i * 8] = oa;
      float4 b0 = ((const float4*)srcB)[2 * i];
      float4 b1 = ((const float4*)srcB)[2 * i + 1];
      u16x8 ob = {f2b(b0.x), f2b(b0.y), f2b(b0.z), f2b(b0.w),
                  f2b(b1.x), f2b(b1.y), f2b(b1.z), f2b(b1.w)};
      *(u16x8*)&Bs[srow][skh + i * 8] = ob;
    }
    __syncthreads();
    #pragma unroll
    for (int kk = 0; kk < 2; ++kk) {
      bf16x8 af[4], bfv[4];
      #pragma unroll
      for (int i = 0; i < 4; ++i)
        af[i] = *(const bf16x8*)&As[wr + i * 16 + fr][kk * 32 + fq * 8];
      #pragma unroll
      for (int j = 0; j < 4; ++j)
        bfv[j] = *(const bf16x8*)&Bs[wc + j * 16 + fr][kk * 32 + fq * 8];
      if (TR) {
        #pragma unroll
        for (int i = 0; i < 4; ++i)
          #pragma unroll
          for (int j = 0; j < 4; ++j)
            acc[i][j] = __builtin_amdgcn_mfma_f32_16x16x32_bf16(bfv[i], af[j], acc[i][j], 0, 0, 0);
      } else {
        #pragma unroll
        for (int i = 0; i < 4; ++i)
          #pragma unroll
          for (int j = 0; j < 4; ++j)
            acc[i][j] = __builtin_amdgcn_mfma_f32_16x16x32_bf16(af[i], bfv[j], acc[i][j], 0, 0, 0);
      }
    }
    __syncthreads();
  }

  if (TR) {
    #pragma unroll
    for (int i = 0; i < 4; ++i)
      #pragma unroll
      for (int j = 0; j < 4; ++j)
        #pragma unroll
        for (int ii = 0; ii < 4; ++ii) {
          const int Nidx = bn + wc + i * 16 + fq * 4 + ii;
          const int Midx = bm + wr + j * 16 + fr;
          const int h = Nidx >> 6, dd = Nidx & (THD - 1);
          const int b = Midx >> 12, tt = Midx & (TT - 1);
          Yb[((size_t)(b * TH + h) * THD + dd) * TT + tt] = f2b(acc[i][j][ii]);
        }
  } else {
    #pragma unroll
    for (int i = 0; i < 4; ++i)
      #pragma unroll
      for (int j = 0; j < 4; ++j)
        #pragma unroll
        for (int ii = 0; ii < 4; ++ii) {
          const int gm = bm + wr + i * 16 + fq * 4 + ii;
          const int gn = bn + wc + j * 16 + fr;
          Yb[(size_t)gm * N + gn] = f2b(acc[i][j][ii]);
        }
  }
}

// ---------------------------------------------------------------------------
// Final GEMM: out = zf @ Wo^T + bo (fp32 out).  (unchanged)
// ---------------------------------------------------------------------------
__global__ __launch_bounds__(256, 2)
void gemm_final(const float* __restrict__ X, const float* __restrict__ W,
                float* __restrict__ Yf, const float* __restrict__ bias)
{
  constexpr int K = TD, N = TD;
  __shared__ unsigned short As[128][72];
  __shared__ unsigned short Bs[128][72];

  const int t    = threadIdx.x;
  const int lane = t & 63, w = t >> 6;
  const int fr = lane & 15, fq = lane >> 4;
  const int wr = (w >> 1) * 64, wc = (w & 1) * 64;
  const int bm = blockIdx.x * 128, bn = blockIdx.y * 128;
  const int srow = t >> 1;
  const int skh  = (t & 1) * 32;

  f32x4 acc[4][4];
  #pragma unroll
  for (int i = 0; i < 4; ++i)
    #pragma unroll
    for (int j = 0; j < 4; ++j)
      acc[i][j] = f32x4{0.f, 0.f, 0.f, 0.f};

  for (int k0 = 0; k0 < K; k0 += 64) {
    const float* srcA = X + (size_t)(bm + srow) * K + k0 + skh;
    const float* srcB = W + (size_t)(bn + srow) * K + k0 + skh;
    #pragma unroll
    for (int i = 0; i < 4; ++i) {
      float4 a0 = ((const float4*)srcA)[2 * i];
      float4 a1 = ((const float4*)srcA)[2 * i + 1];
      u16x8 oa = {f2b(a0.x), f2b(a0.y), f2b(a0.z), f2b(a0.w),
                  f2b(a1.x), f2b(a1.y), f2b(a1.z), f2b(a1.w)};
      *(u16x8*)&As[srow][skh + i * 8] = oa;
      float4 b0 = ((const float4*)srcB)[2 * i];
      float4 b1 = ((const float4*)srcB)[2 * i + 1];
      u16x8 ob = {f2b(b0.x), f2b(b0.y), f2b(b0.z), f2b(b0.w),
                  f2b(b1.x), f2b(b1.y), f2b(b1.z), f2b(b1.w)};
      *(u16x8*)&Bs[srow][skh + i * 8] = ob;
    }
    __syncthreads();
    #pragma unroll
    for (int kk = 0; kk < 2; ++kk) {
      bf16x8 af[4], bfv[4];
      #pragma unroll
      for (int i = 0; i < 4; ++i)
        af[i] = *(const bf16x8*)&As[wr + i * 16 + fr][kk * 32 + fq * 8];
      #pragma unroll
      for (int j = 0; j < 4; ++j)
        bfv[j] = *(const bf16x8*)&Bs[wc + j * 16 + fr][kk * 32 + fq * 8];
      #pragma unroll
      for (int i = 0; i < 4; ++i)
        #pragma unroll
        for (int j = 0; j < 4; ++j)
          acc[i][j] = __builtin_amdgcn_mfma_f32_16x16x32_bf16(af[i], bfv[j], acc[i][j], 0, 0, 0);
    }
    __syncthreads();
  }

  #pragma unroll
  for (int i = 0; i < 4; ++i)
    #pragma unroll
    for (int j = 0; j < 4; ++j)
      #pragma unroll
      for (int ii = 0; ii < 4; ++ii) {
        const int gm = bm + wr + i * 16 + fq * 4 + ii;
        const int gn = bn + wc + j * 16 + fr;
        Yf[(size_t)gm * N + gn] = acc[i][j][ii] + bias[gn];
      }
}

// ---------------------------------------------------------------------------
// Fused attention v11: r10 pass 1 (PV + lsum, no stores) + burst-store pass 2.
// Pass 2 accumulates P for 256 kv (8 tiles) in a per-wave LDS buffer
// Ps[16][268] f32, then stores 16 rows x 1KB CONTIGUOUS (64 lanes x f32x4)
// -> full-DRAM-page bursts instead of 128B fragments.
// LDS: Ks[2][32][72] (9KB) + region2 = max(VTs pass1 10KB, Ps 68.6KB) =
// 77.8 KB -> 2 blocks/CU at launch_bounds(256,2) (VGPR cap 256, no spill).
// XCD swizzle unchanged.
// ---------------------------------------------------------------------------
__global__ __launch_bounds__(256, 2)
void attn_fused(const unsigned short* __restrict__ Qb,
                const unsigned short* __restrict__ Kb,
                const unsigned short* __restrict__ VTg,
                float* __restrict__ attnO, float* __restrict__ Z)
{
  // Ks @0 (9216B) | region2 @9216: VTs[2][64][40] u16 (pass1) / Ps[4][16][268]
  // f32 (pass2) -> total 9216 + 68608 = 77824 B
  __shared__ __align__(16) char smem_[77824];
  auto Ks  = (unsigned short (*)[32][72])smem_;
  auto VTs = (unsigned short (*)[64][40])(smem_ + 9216);
  auto Ps  = (float (*)[16][268])(smem_ + 9216);

  const int t    = threadIdx.x;
  const int lane = t & 63, w = t >> 6;         // w = 0..3 (q sixteenth)
  const int fr = lane & 15, fq = lane >> 4;

  const int d  = blockIdx.x;                   // 0..1023
  const int bh = 2 * (d & 7) + ((d >> 3) & 1); // 2 bh per XCD
  const int q0 = (d >> 4) * 64;
  const int b  = bh >> 3, h = bh & 7;

  const size_t rowKV  = ((size_t)(b * TT)) * TD + h * THD;
  const size_t vtBase = (size_t)bh * THD * TT;

  const int trK = t >> 3, tcK = (t & 7) * 8;   // K staging 32x64
  const int trV = t >> 2, tcV = (t & 3) * 8;   // VT staging 64x32

  auto loadK = [&](int kv0, u16x8& r) {
    r = *(const u16x8*)(Kb + rowKV + (size_t)(kv0 + trK) * TD + tcK);
  };
  auto loadVT = [&](int kv0, u16x8& r) {
    r = *(const u16x8*)(VTg + vtBase + (size_t)trV * TT + kv0 + tcV);
  };
  auto writeK  = [&](int buf, const u16x8& r) { *(u16x8*)&Ks[buf][trK][tcK]  = r; };
  auto writeVT = [&](int buf, const u16x8& r) { *(u16x8*)&VTs[buf][trV][tcV] = r; };

  // Q held in registers (B-operand of swapped QK; row = q = w*16+fr)
  const unsigned short* qsrc = Qb + ((size_t)(b * TT + q0 + w * 16 + fr)) * TD + h * THD;
  bf16x8 aq[2];
  aq[0] = *(const bf16x8*)(qsrc + fq * 8);
  aq[1] = *(const bf16x8*)(qsrc + 32 + fq * 8);

  constexpr int KVB = 32;
  constexpr int NT = TT / KVB;                 // 128 kv tiles
  constexpr float K2 = 0.18033688011112042f;   // (1/8) * log2(e)

  u16x8 kr, vr;
  loadK(0, kr);
  loadVT(0, vr);
  writeK(0, kr);
  writeVT(0, vr);
  lgkm_barrier();

  // ---- pass 1: lsum + unnormalized PV (no global stores) ----
  float lsum = 0.f;
  f32x4 accz[4];
  #pragma unroll
  for (int n = 0; n < 4; ++n) accz[n] = f32x4{0.f, 0.f, 0.f, 0.f};

  for (int j = 0; j < NT; ++j) {
    const int cur = j & 1;
    if (j + 1 < NT) {
      loadK((j + 1) * KVB, kr);
      loadVT((j + 1) * KVB, vr);
    }
    f32x4 sv[2];
    __builtin_amdgcn_s_setprio(1);
    #pragma unroll
    for (int n = 0; n < 2; ++n) {
      f32x4 s = f32x4{0.f, 0.f, 0.f, 0.f};
      #pragma unroll
      for (int kk = 0; kk < 2; ++kk) {
        bf16x8 ak = *(const bf16x8*)&Ks[cur][n * 16 + fr][kk * 32 + fq * 8];
        s = __builtin_amdgcn_mfma_f32_16x16x32_bf16(ak, aq[kk], s, 0, 0, 0);
      }
      sv[n] = s;
    }
    __builtin_amdgcn_s_setprio(0);
    float p[2][4];
    #pragma unroll
    for (int n = 0; n < 2; ++n)
      #pragma unroll
      for (int i = 0; i < 4; ++i) {
        p[n][i] = __builtin_amdgcn_exp2f(sv[n][i] * K2);
        lsum += p[n][i];
      }
    uint4v pav = {cvtpk(p[0][0], p[0][1]), cvtpk(p[0][2], p[0][3]),
                  cvtpk(p[1][0], p[1][1]), cvtpk(p[1][2], p[1][3])};
    bf16x8 ap = __builtin_bit_cast(bf16x8, pav);
    __builtin_amdgcn_s_setprio(1);
    #pragma unroll
    for (int df = 0; df < 4; ++df) {
      uint2v lo = *(const uint2v*)&VTs[cur][df * 16 + fr][fq * 4];
      uint2v hi = *(const uint2v*)&VTs[cur][df * 16 + fr][16 + fq * 4];
      uint4v bvv = {lo[0], lo[1], hi[0], hi[1]};
      accz[df] = __builtin_amdgcn_mfma_f32_16x16x32_bf16(
          ap, __builtin_bit_cast(bf16x8, bvv), accz[df], 0, 0, 0);
    }
    __builtin_amdgcn_s_setprio(0);
    if (j + 1 < NT) {
      writeK(cur ^ 1, kr);
      writeVT(cur ^ 1, vr);
    }
    lgkm_barrier();
  }

  // full row sums (q = w*16+fr lane-local; kv split across fq)
  lsum += __shfl_xor(lsum, 16, 64);
  lsum += __shfl_xor(lsum, 32, 64);

  // Z = accz / lsum; accz row i is q = w*16 + fq*4 + i
  float rls[4];
  #pragma unroll
  for (int i = 0; i < 4; ++i)
    rls[i] = 1.0f / __shfl(lsum, fq * 4 + i, 64);
  const size_t zbase = ((size_t)(b * TT + q0 + w * 16 + fq * 4)) * TD + h * THD + fr;
  #pragma unroll
  for (int df = 0; df < 4; ++df)
    #pragma unroll
    for (int i = 0; i < 4; ++i)
      Z[zbase + (size_t)i * TD + df * 16] = accz[df][i] * rls[i];

  // ---- pass 2: burst-store streamer ----
  const float l2i = -__log2f(lsum);
  loadK(0, kr);
  writeK(0, kr);
  lgkm_barrier();      // also fences pass-1 VTs reads before Ps overwrites

  for (int st = 0; st < 16; ++st) {            // 16 super-tiles of 256 kv
    #pragma unroll
    for (int jj = 0; jj < 8; ++jj) {
      const int j = st * 8 + jj;
      const int cur = j & 1;
      if (j + 1 < NT) loadK((j + 1) * KVB, kr);
      f32x4 sv[2];
      __builtin_amdgcn_s_setprio(1);
      #pragma unroll
      for (int n = 0; n < 2; ++n) {
        f32x4 s = f32x4{0.f, 0.f, 0.f, 0.f};
        #pragma unroll
        for (int kk = 0; kk < 2; ++kk) {
          bf16x8 ak = *(const bf16x8*)&Ks[cur][n * 16 + fr][kk * 32 + fq * 8];
          s = __builtin_amdgcn_mfma_f32_16x16x32_bf16(ak, aq[kk], s, 0, 0, 0);
        }
        sv[n] = s;
      }
      __builtin_amdgcn_s_setprio(0);
      #pragma unroll
      for (int n = 0; n < 2; ++n) {
        f32x4 pv4 = {__builtin_amdgcn_exp2f(fmaf(sv[n][0], K2, l2i)),
                     __builtin_amdgcn_exp2f(fmaf(sv[n][1], K2, l2i)),
                     __builtin_amdgcn_exp2f(fmaf(sv[n][2], K2, l2i)),
                     __builtin_amdgcn_exp2f(fmaf(sv[n][3], K2, l2i))};
        *(f32x4*)&Ps[w][fr][jj * 32 + n * 16 + fq * 4] = pv4;
      }
      if (j + 1 < NT) writeK(cur ^ 1, kr);
      lgkm_barrier();
    }
    // burst store: 16 rows x 1KB contiguous (64 lanes x f32x4 each)
    {
      float* dst0 = attnO + ((size_t)bh * TT + q0 + w * 16) * TT + st * 256 + lane * 4;
      #pragma unroll
      for (int r = 0; r < 16; ++r) {
        f32x4 v = *(const f32x4*)&Ps[w][r][lane * 4];
        *(f32x4*)(dst0 + (size_t)r * TT) = v;
      }
    }
  }
}

// ---------------------------------------------------------------------------
extern "C" void kernel_launch(void* const* d_in, const int* in_sizes, int n_in,
                              void* d_out, int out_size, void* d_ws, size_t ws_size,
                              hipStream_t stream) {
  const float* queries = (const float*)d_in[0];
  const float* keys    = (const float*)d_in[1];
  const float* values  = (const float*)d_in[2];
  const float* Wq = (const float*)d_in[3];
  const float* Wk = (const float*)d_in[4];
  const float* Wv = (const float*)d_in[5];
  const float* Wo = (const float*)d_in[6];
  const float* bo = (const float*)d_in[7];

  float* out  = (float*)d_out;                       // [2,4096,512]
  float* attn = out + (size_t)TM * TD;               // [2,8,4096,4096]

  unsigned short* qb = (unsigned short*)d_ws;
  unsigned short* kb = qb + (size_t)TM * TD;
  unsigned short* vt = kb + (size_t)TM * TD;
  float*          zf = (float*)(vt + (size_t)TM * TD);

  proj_qkv<<<dim3(TM / 128, TD / 128, 3), 256, 0, stream>>>(
      queries, keys, values, Wq, Wk, Wv, qb, kb, vt);

  attn_fused<<<dim3(1024), 256, 0, stream>>>(qb, kb, vt, attn, zf);

  gemm_final<<<dim3(TM / 128, TD / 128), 256, 0, stream>>>(zf, Wo, out, bo);
}

// Round 12
// 501.665 us; speedup vs baseline: 1.1060x; 1.1060x over previous
//
#include <hip/hip_runtime.h>

typedef __attribute__((ext_vector_type(8))) short bf16x8;
typedef __attribute__((ext_vector_type(8))) unsigned short u16x8;
typedef __attribute__((ext_vector_type(4))) float f32x4;
typedef __attribute__((ext_vector_type(2))) unsigned uint2v;
typedef __attribute__((ext_vector_type(4))) unsigned uint4v;

#define DEVINL __device__ __forceinline__

constexpr int TB = 2;        // batch
constexpr int TT = 4096;     // seq len
constexpr int TD = 512;      // model dim
constexpr int TH = 8;        // heads
constexpr int THD = 64;      // head dim
constexpr int TM = TB * TT;  // 8192 flattened rows

// fp32 -> bf16 round-to-nearest-even
DEVINL unsigned short f2b(float f) {
  unsigned u = __builtin_bit_cast(unsigned, f);
  u += 0x7FFFu + ((u >> 16) & 1u);
  return (unsigned short)(u >> 16);
}

// pack 2 f32 -> 2 bf16 in one dword (lo -> low16, hi -> high16), RNE
DEVINL unsigned cvtpk(float lo, float hi) {
  unsigned r;
  asm("v_cvt_pk_bf16_f32 %0, %1, %2" : "=v"(r) : "v"(lo), "v"(hi));
  return r;
}

// barrier that only waits LDS ops (global stores may stay in flight)
DEVINL void lgkm_barrier() {
  asm volatile("s_waitcnt lgkmcnt(0)" ::: "memory");
  __builtin_amdgcn_s_barrier();
  __builtin_amdgcn_sched_barrier(0);
}

// ---------------------------------------------------------------------------
// Fused Q/K/V projection (unchanged from r10).
// ---------------------------------------------------------------------------
__global__ __launch_bounds__(256, 2)
void proj_qkv(const float* __restrict__ Xq, const float* __restrict__ Xk,
              const float* __restrict__ Xv, const float* __restrict__ Wq,
              const float* __restrict__ Wk, const float* __restrict__ Wv,
              unsigned short* __restrict__ qb, unsigned short* __restrict__ kb,
              unsigned short* __restrict__ vt)
{
  constexpr int K = TD, N = TD;
  __shared__ unsigned short As[128][72];
  __shared__ unsigned short Bs[128][72];

  const int z = blockIdx.z;
  const float* X = (z == 0) ? Xq : (z == 1) ? Xk : Xv;
  const float* W = (z == 0) ? Wq : (z == 1) ? Wk : Wv;
  unsigned short* Yb = (z == 0) ? qb : (z == 1) ? kb : vt;
  const bool TR = (z == 2);

  const int t    = threadIdx.x;
  const int lane = t & 63, w = t >> 6;
  const int fr = lane & 15, fq = lane >> 4;
  const int wr = (w >> 1) * 64, wc = (w & 1) * 64;
  const int bm = blockIdx.x * 128, bn = blockIdx.y * 128;
  const int srow = t >> 1;
  const int skh  = (t & 1) * 32;

  f32x4 acc[4][4];
  #pragma unroll
  for (int i = 0; i < 4; ++i)
    #pragma unroll
    for (int j = 0; j < 4; ++j)
      acc[i][j] = f32x4{0.f, 0.f, 0.f, 0.f};

  for (int k0 = 0; k0 < K; k0 += 64) {
    const float* srcA = X + (size_t)(bm + srow) * K + k0 + skh;
    const float* srcB = W + (size_t)(bn + srow) * K + k0 + skh;
    #pragma unroll
    for (int i = 0; i < 4; ++i) {
      float4 a0 = ((const float4*)srcA)[2 * i];
      float4 a1 = ((const float4*)srcA)[2 * i + 1];
      u16x8 oa = {f2b(a0.x), f2b(a0.y), f2b(a0.z), f2b(a0.w),
                  f2b(a1.x), f2b(a1.y), f2b(a1.z), f2b(a1.w)};
      *(u16x8*)&As[srow][skh + i * 8] = oa;
      float4 b0 = ((const float4*)srcB)[2 * i];
      float4 b1 = ((const float4*)srcB)[2 * i + 1];
      u16x8 ob = {f2b(b0.x), f2b(b0.y), f2b(b0.z), f2b(b0.w),
                  f2b(b1.x), f2b(b1.y), f2b(b1.z), f2b(b1.w)};
      *(u16x8*)&Bs[srow][skh + i * 8] = ob;
    }
    __syncthreads();
    #pragma unroll
    for (int kk = 0; kk < 2; ++kk) {
      bf16x8 af[4], bfv[4];
      #pragma unroll
      for (int i = 0; i < 4; ++i)
        af[i] = *(const bf16x8*)&As[wr + i * 16 + fr][kk * 32 + fq * 8];
      #pragma unroll
      for (int j = 0; j < 4; ++j)
        bfv[j] = *(const bf16x8*)&Bs[wc + j * 16 + fr][kk * 32 + fq * 8];
      if (TR) {
        #pragma unroll
        for (int i = 0; i < 4; ++i)
          #pragma unroll
          for (int j = 0; j < 4; ++j)
            acc[i][j] = __builtin_amdgcn_mfma_f32_16x16x32_bf16(bfv[i], af[j], acc[i][j], 0, 0, 0);
      } else {
        #pragma unroll
        for (int i = 0; i < 4; ++i)
          #pragma unroll
          for (int j = 0; j < 4; ++j)
            acc[i][j] = __builtin_amdgcn_mfma_f32_16x16x32_bf16(af[i], bfv[j], acc[i][j], 0, 0, 0);
      }
    }
    __syncthreads();
  }

  if (TR) {
    #pragma unroll
    for (int i = 0; i < 4; ++i)
      #pragma unroll
      for (int j = 0; j < 4; ++j)
        #pragma unroll
        for (int ii = 0; ii < 4; ++ii) {
          const int Nidx = bn + wc + i * 16 + fq * 4 + ii;
          const int Midx = bm + wr + j * 16 + fr;
          const int h = Nidx >> 6, dd = Nidx & (THD - 1);
          const int b = Midx >> 12, tt = Midx & (TT - 1);
          Yb[((size_t)(b * TH + h) * THD + dd) * TT + tt] = f2b(acc[i][j][ii]);
        }
  } else {
    #pragma unroll
    for (int i = 0; i < 4; ++i)
      #pragma unroll
      for (int j = 0; j < 4; ++j)
        #pragma unroll
        for (int ii = 0; ii < 4; ++ii) {
          const int gm = bm + wr + i * 16 + fq * 4 + ii;
          const int gn = bn + wc + j * 16 + fr;
          Yb[(size_t)gm * N + gn] = f2b(acc[i][j][ii]);
        }
  }
}

// ---------------------------------------------------------------------------
// Final GEMM: out = zf @ Wo^T + bo (fp32 out).  (unchanged)
// ---------------------------------------------------------------------------
__global__ __launch_bounds__(256, 2)
void gemm_final(const float* __restrict__ X, const float* __restrict__ W,
                float* __restrict__ Yf, const float* __restrict__ bias)
{
  constexpr int K = TD, N = TD;
  __shared__ unsigned short As[128][72];
  __shared__ unsigned short Bs[128][72];

  const int t    = threadIdx.x;
  const int lane = t & 63, w = t >> 6;
  const int fr = lane & 15, fq = lane >> 4;
  const int wr = (w >> 1) * 64, wc = (w & 1) * 64;
  const int bm = blockIdx.x * 128, bn = blockIdx.y * 128;
  const int srow = t >> 1;
  const int skh  = (t & 1) * 32;

  f32x4 acc[4][4];
  #pragma unroll
  for (int i = 0; i < 4; ++i)
    #pragma unroll
    for (int j = 0; j < 4; ++j)
      acc[i][j] = f32x4{0.f, 0.f, 0.f, 0.f};

  for (int k0 = 0; k0 < K; k0 += 64) {
    const float* srcA = X + (size_t)(bm + srow) * K + k0 + skh;
    const float* srcB = W + (size_t)(bn + srow) * K + k0 + skh;
    #pragma unroll
    for (int i = 0; i < 4; ++i) {
      float4 a0 = ((const float4*)srcA)[2 * i];
      float4 a1 = ((const float4*)srcA)[2 * i + 1];
      u16x8 oa = {f2b(a0.x), f2b(a0.y), f2b(a0.z), f2b(a0.w),
                  f2b(a1.x), f2b(a1.y), f2b(a1.z), f2b(a1.w)};
      *(u16x8*)&As[srow][skh + i * 8] = oa;
      float4 b0 = ((const float4*)srcB)[2 * i];
      float4 b1 = ((const float4*)srcB)[2 * i + 1];
      u16x8 ob = {f2b(b0.x), f2b(b0.y), f2b(b0.z), f2b(b0.w),
                  f2b(b1.x), f2b(b1.y), f2b(b1.z), f2b(b1.w)};
      *(u16x8*)&Bs[srow][skh + i * 8] = ob;
    }
    __syncthreads();
    #pragma unroll
    for (int kk = 0; kk < 2; ++kk) {
      bf16x8 af[4], bfv[4];
      #pragma unroll
      for (int i = 0; i < 4; ++i)
        af[i] = *(const bf16x8*)&As[wr + i * 16 + fr][kk * 32 + fq * 8];
      #pragma unroll
      for (int j = 0; j < 4; ++j)
        bfv[j] = *(const bf16x8*)&Bs[wc + j * 16 + fr][kk * 32 + fq * 8];
      #pragma unroll
      for (int i = 0; i < 4; ++i)
        #pragma unroll
        for (int j = 0; j < 4; ++j)
          acc[i][j] = __builtin_amdgcn_mfma_f32_16x16x32_bf16(af[i], bfv[j], acc[i][j], 0, 0, 0);
    }
    __syncthreads();
  }

  #pragma unroll
  for (int i = 0; i < 4; ++i)
    #pragma unroll
    for (int j = 0; j < 4; ++j)
      #pragma unroll
      for (int ii = 0; ii < 4; ++ii) {
        const int gm = bm + wr + i * 16 + fq * 4 + ii;
        const int gn = bn + wc + j * 16 + fr;
        Yf[(size_t)gm * N + gn] = acc[i][j][ii] + bias[gn];
      }
}

// ---------------------------------------------------------------------------
// Fused attention v12 = r10 pass 1 (PV + lsum) + PHASE-STAGGERED pass 2.
// Mechanism: attn rows are 16KB apart (multiple of HBM channel interleave);
// all blocks sweeping kv from j=0 in lockstep hit the same channel phase
// device-wide -> ~1/3 of write BW. Pass 2 gives each (block,wave) a phase
// phi = (37*d + 32*w) & 127 and processes tiles j = (jj+phi)&127, spreading
// concurrent writes across all channel positions (fillBuffer-like).
// Per-wave K staging KsW[4][2][32][72] (36.9 KB, overlaid on pass-1 LDS)
// makes per-wave phases possible and removes ALL pass-2 barriers.
// LDS 36.9 KB, launch_bounds(256,4) -> 4 blocks/CU, grid resident in 1 round.
// ---------------------------------------------------------------------------
__global__ __launch_bounds__(256, 4)
void attn_fused(const unsigned short* __restrict__ Qb,
                const unsigned short* __restrict__ Kb,
                const unsigned short* __restrict__ VTg,
                float* __restrict__ attnO, float* __restrict__ Z)
{
  // pass 1: Ks[2][32][72] @0 (9216B) | VTs[2][64][40] @9216 (10240B)
  // pass 2: KsW[4][2][32][72] @0 (36864B) per-wave double buffers (overlay)
  __shared__ __align__(16) char smem_[36864];
  auto Ks  = (unsigned short (*)[32][72])smem_;
  auto VTs = (unsigned short (*)[64][40])(smem_ + 9216);
  auto KsW = (unsigned short (*)[2][32][72])smem_;

  const int t    = threadIdx.x;
  const int lane = t & 63, w = t >> 6;         // w = 0..3 (q sixteenth)
  const int fr = lane & 15, fq = lane >> 4;

  const int d  = blockIdx.x;                   // 0..1023
  const int bh = 2 * (d & 7) + ((d >> 3) & 1); // 2 bh per XCD
  const int q0 = (d >> 4) * 64;
  const int b  = bh >> 3, h = bh & 7;

  const size_t rowKV  = ((size_t)(b * TT)) * TD + h * THD;
  const size_t vtBase = (size_t)bh * THD * TT;

  const int trK = t >> 3, tcK = (t & 7) * 8;   // K staging 32x64 (block)
  const int trV = t >> 2, tcV = (t & 3) * 8;   // VT staging 64x32 (block)

  auto loadK = [&](int kv0, u16x8& r) {
    r = *(const u16x8*)(Kb + rowKV + (size_t)(kv0 + trK) * TD + tcK);
  };
  auto loadVT = [&](int kv0, u16x8& r) {
    r = *(const u16x8*)(VTg + vtBase + (size_t)trV * TT + kv0 + tcV);
  };
  auto writeK  = [&](int buf, const u16x8& r) { *(u16x8*)&Ks[buf][trK][tcK]  = r; };
  auto writeVT = [&](int buf, const u16x8& r) { *(u16x8*)&VTs[buf][trV][tcV] = r; };

  // Q held in registers (B-operand of swapped QK; row = q = w*16+fr)
  const unsigned short* qsrc = Qb + ((size_t)(b * TT + q0 + w * 16 + fr)) * TD + h * THD;
  bf16x8 aq[2];
  aq[0] = *(const bf16x8*)(qsrc + fq * 8);
  aq[1] = *(const bf16x8*)(qsrc + 32 + fq * 8);

  constexpr int KVB = 32;
  constexpr int NT = TT / KVB;                 // 128 kv tiles
  constexpr float K2 = 0.18033688011112042f;   // (1/8) * log2(e)

  u16x8 kr, vr;
  loadK(0, kr);
  loadVT(0, vr);
  writeK(0, kr);
  writeVT(0, vr);
  lgkm_barrier();

  // ---- pass 1: lsum + unnormalized PV (no global stores) ----
  float lsum = 0.f;
  f32x4 accz[4];
  #pragma unroll
  for (int n = 0; n < 4; ++n) accz[n] = f32x4{0.f, 0.f, 0.f, 0.f};

  for (int j = 0; j < NT; ++j) {
    const int cur = j & 1;
    if (j + 1 < NT) {
      loadK((j + 1) * KVB, kr);
      loadVT((j + 1) * KVB, vr);
    }
    f32x4 sv[2];
    __builtin_amdgcn_s_setprio(1);
    #pragma unroll
    for (int n = 0; n < 2; ++n) {
      f32x4 s = f32x4{0.f, 0.f, 0.f, 0.f};
      #pragma unroll
      for (int kk = 0; kk < 2; ++kk) {
        bf16x8 ak = *(const bf16x8*)&Ks[cur][n * 16 + fr][kk * 32 + fq * 8];
        s = __builtin_amdgcn_mfma_f32_16x16x32_bf16(ak, aq[kk], s, 0, 0, 0);
      }
      sv[n] = s;
    }
    __builtin_amdgcn_s_setprio(0);
    float p[2][4];
    #pragma unroll
    for (int n = 0; n < 2; ++n)
      #pragma unroll
      for (int i = 0; i < 4; ++i) {
        p[n][i] = __builtin_amdgcn_exp2f(sv[n][i] * K2);
        lsum += p[n][i];
      }
    uint4v pav = {cvtpk(p[0][0], p[0][1]), cvtpk(p[0][2], p[0][3]),
                  cvtpk(p[1][0], p[1][1]), cvtpk(p[1][2], p[1][3])};
    bf16x8 ap = __builtin_bit_cast(bf16x8, pav);
    __builtin_amdgcn_s_setprio(1);
    #pragma unroll
    for (int df = 0; df < 4; ++df) {
      uint2v lo = *(const uint2v*)&VTs[cur][df * 16 + fr][fq * 4];
      uint2v hi = *(const uint2v*)&VTs[cur][df * 16 + fr][16 + fq * 4];
      uint4v bvv = {lo[0], lo[1], hi[0], hi[1]};
      accz[df] = __builtin_amdgcn_mfma_f32_16x16x32_bf16(
          ap, __builtin_bit_cast(bf16x8, bvv), accz[df], 0, 0, 0);
    }
    __builtin_amdgcn_s_setprio(0);
    if (j + 1 < NT) {
      writeK(cur ^ 1, kr);
      writeVT(cur ^ 1, vr);
    }
    lgkm_barrier();
  }

  // full row sums (q = w*16+fr lane-local; kv split across fq)
  lsum += __shfl_xor(lsum, 16, 64);
  lsum += __shfl_xor(lsum, 32, 64);

  // Z = accz / lsum; accz row i is q = w*16 + fq*4 + i
  float rls[4];
  #pragma unroll
  for (int i = 0; i < 4; ++i)
    rls[i] = 1.0f / __shfl(lsum, fq * 4 + i, 64);
  const size_t zbase = ((size_t)(b * TT + q0 + w * 16 + fq * 4)) * TD + h * THD + fr;
  #pragma unroll
  for (int df = 0; df < 4; ++df)
    #pragma unroll
    for (int i = 0; i < 4; ++i)
      Z[zbase + (size_t)i * TD + df * 16] = accz[df][i] * rls[i];

  // ---- pass 2: phase-staggered store streamer (per-wave, barrier-free) ----
  const float l2i = -__log2f(lsum);
  __syncthreads();                 // retire pass-1 LDS reads before overlay

  const int phase = (37 * d + 32 * w) & (NT - 1);
  // per-wave staging: lane covers row i*8 + (lane>>3), cols (lane&7)*8..+8
  const int prow = lane >> 3, pcol = (lane & 7) * 8;
  u16x8 kr4[4];
  auto loadKW = [&](int kvt) {
    #pragma unroll
    for (int i = 0; i < 4; ++i)
      kr4[i] = *(const u16x8*)(Kb + rowKV +
                 (size_t)(kvt * KVB + i * 8 + prow) * TD + pcol);
  };
  auto writeKW = [&](int buf) {
    #pragma unroll
    for (int i = 0; i < 4; ++i)
      *(u16x8*)&KsW[w][buf][i * 8 + prow][pcol] = kr4[i];
  };

  loadKW(phase);
  writeKW(0);

  float* arow = attnO + ((size_t)bh * TT + q0 + w * 16 + fr) * TT + fq * 4;

  for (int jj = 0; jj < NT; ++jj) {
    const int cur = jj & 1;
    const int j = (jj + phase) & (NT - 1);
    if (jj + 1 < NT) loadKW((jj + 1 + phase) & (NT - 1));
    f32x4 sv[2];
    __builtin_amdgcn_s_setprio(1);
    #pragma unroll
    for (int n = 0; n < 2; ++n) {
      f32x4 s = f32x4{0.f, 0.f, 0.f, 0.f};
      #pragma unroll
      for (int kk = 0; kk < 2; ++kk) {
        bf16x8 ak = *(const bf16x8*)&KsW[w][cur][n * 16 + fr][kk * 32 + fq * 8];
        s = __builtin_amdgcn_mfma_f32_16x16x32_bf16(ak, aq[kk], s, 0, 0, 0);
      }
      sv[n] = s;
    }
    __builtin_amdgcn_s_setprio(0);
    #pragma unroll
    for (int n = 0; n < 2; ++n) {
      f32x4 pv4 = {__builtin_amdgcn_exp2f(fmaf(sv[n][0], K2, l2i)),
                   __builtin_amdgcn_exp2f(fmaf(sv[n][1], K2, l2i)),
                   __builtin_amdgcn_exp2f(fmaf(sv[n][2], K2, l2i)),
                   __builtin_amdgcn_exp2f(fmaf(sv[n][3], K2, l2i))};
      *(f32x4*)(arow + j * KVB + n * 16) = pv4;
    }
    if (jj + 1 < NT) writeKW(cur ^ 1);
  }
}

// ---------------------------------------------------------------------------
extern "C" void kernel_launch(void* const* d_in, const int* in_sizes, int n_in,
                              void* d_out, int out_size, void* d_ws, size_t ws_size,
                              hipStream_t stream) {
  const float* queries = (const float*)d_in[0];
  const float* keys    = (const float*)d_in[1];
  const float* values  = (const float*)d_in[2];
  const float* Wq = (const float*)d_in[3];
  const float* Wk = (const float*)d_in[4];
  const float* Wv = (const float*)d_in[5];
  const float* Wo = (const float*)d_in[6];
  const float* bo = (const float*)d_in[7];

  float* out  = (float*)d_out;                       // [2,4096,512]
  float* attn = out + (size_t)TM * TD;               // [2,8,4096,4096]

  unsigned short* qb = (unsigned short*)d_ws;
  unsigned short* kb = qb + (size_t)TM * TD;
  unsigned short* vt = kb + (size_t)TM * TD;
  float*          zf = (float*)(vt + (size_t)TM * TD);

  proj_qkv<<<dim3(TM / 128, TD / 128, 3), 256, 0, stream>>>(
      queries, keys, values, Wq, Wk, Wv, qb, kb, vt);

  attn_fused<<<dim3(1024), 256, 0, stream>>>(qb, kb, vt, attn, zf);

  gemm_final<<<dim3(TM / 128, TD / 128), 256, 0, stream>>>(zf, Wo, out, bo);
}